// Round 1
// baseline (406.367 us; speedup 1.0000x reference)
//
#include <hip/hip_runtime.h>
#include <stdint.h>

// ---------------------------------------------------------------------------
// RowParallelLinearSparse: out[M,N] = x[M,K] · (W ⊙ nm_mask(W))[N,K]^T + bias
// M=16384 (S*B), N=O=2048, K=H=2048.  bf16 MFMA.
//
// GEMM: 256x256 tile, BK=32, 8 waves (2Mx4N), ring-4 LDS buffers (128 KiB),
// counted s_waitcnt vmcnt(8) (never 0 in steady state), one raw s_barrier
// per K-tile, setprio(1) around the MFMA cluster, XOR-swizzled LDS
// (conflict-free: chunk ^ ((row>>1)&3) on 64B rows, both-sides swizzle via
// pre-swizzled global source for global_load_lds), XCD-ownership N-column
// mapping (N/256 == 8 == #XCDs -> B slice L2-resident per XCD).
//
// Race-freedom of the ring: STAGE(t+4)->buf[t&3] issues after barrier t+1;
// all waves' ds_reads of tile t complete (into regs, via compiler lgkmcnt
// before MFMA use) before they pass that barrier; async LDS writes cannot
// land before issue.
// ---------------------------------------------------------------------------

typedef short  bf16x8  __attribute__((ext_vector_type(8)));
typedef float  floatx4 __attribute__((ext_vector_type(4)));

#define AS1 __attribute__((address_space(1)))
#define AS3 __attribute__((address_space(3)))

__device__ __forceinline__ void async_copy16(const void* g, void* l) {
    __builtin_amdgcn_global_load_lds((const AS1 unsigned int*)g,
                                     (AS3 unsigned int*)l, 16, 0, 0);
}

__device__ __forceinline__ unsigned short f2bf(float f) {
    union { float f; unsigned int u; } v;
    v.f = f;
    unsigned int r = (v.u + 0x7fffu + ((v.u >> 16) & 1u)) >> 16;  // RNE
    return (unsigned short)r;
}

// --- x: fp32 -> bf16, 8 elements/thread --------------------------------------
__global__ void cvt_bf16_x8(const float4* __restrict__ in,
                            uint4* __restrict__ out, long n8) {
    long i = (long)blockIdx.x * blockDim.x + threadIdx.x;
    if (i >= n8) return;
    float4 f0 = in[2 * i];
    float4 f1 = in[2 * i + 1];
    uint4 o;
    o.x = (unsigned)f2bf(f0.x) | ((unsigned)f2bf(f0.y) << 16);
    o.y = (unsigned)f2bf(f0.z) | ((unsigned)f2bf(f0.w) << 16);
    o.z = (unsigned)f2bf(f1.x) | ((unsigned)f2bf(f1.y) << 16);
    o.w = (unsigned)f2bf(f1.z) | ((unsigned)f2bf(f1.w) << 16);
    out[i] = o;
}

// --- W: 2:4 mask (zero 2 smallest |w| per group of 4, stable-argsort tie
//        order) -> bf16. One thread per group. -------------------------------
__global__ void sparsify_w(const float4* __restrict__ W,
                           unsigned long long* __restrict__ Wb, int ngroups) {
    int g = blockIdx.x * blockDim.x + threadIdx.x;
    if (g >= ngroups) return;
    float4 w4 = W[g];
    float v[4] = {w4.x, w4.y, w4.z, w4.w};
    float a[4] = {fabsf(w4.x), fabsf(w4.y), fabsf(w4.z), fabsf(w4.w)};
    unsigned long long packed = 0;
#pragma unroll
    for (int i = 0; i < 4; i++) {
        int rank = 0;
#pragma unroll
        for (int j = 0; j < 4; j++)
            rank += (a[j] < a[i]) || (a[j] == a[i] && j < i);
        unsigned short b = (rank >= 2) ? f2bf(v[i]) : (unsigned short)0;
        packed |= ((unsigned long long)b) << (16 * i);
    }
    Wb[g] = packed;
}

// --- bf16 B^T GEMM: 256x256 tile, BK=32, ring-4 counted-vmcnt pipeline. -----
__global__ __launch_bounds__(512, 2) void gemm_bt_bf16_256(
    const unsigned short* __restrict__ A,   // [M,K] bf16
    const unsigned short* __restrict__ B,   // [N,K] bf16 (sparse W)
    const float* __restrict__ bias,         // [N]
    float* __restrict__ C,                  // [M,N] fp32
    int M, int N, int K) {
    // 4 ring buffers x (256 rows x 32 cols bf16) for A and B = 128 KiB total.
    __shared__ unsigned short lA[4][256 * 32];
    __shared__ unsigned short lB[4][256 * 32];

    const int tid  = threadIdx.x;
    const int w    = tid >> 6;       // wave 0..7
    const int lane = tid & 63;
    const int wr   = w >> 2;         // 0..1 : M-half of tile
    const int wc   = w & 3;          // 0..3 : N-quarter of tile

    // XCD-ownership mapping: 8 N-blocks == 8 XCDs (HW round-robins id&7).
    const int id  = blockIdx.x;
    const int nbx = N >> 8;
    int bm, bn;
    if (nbx == 8) {
        bn = (id & 7) << 8;
        bm = (id >> 3) << 8;
    } else {                          // fallback: plain decompose
        bn = (id % nbx) << 8;
        bm = (id / nbx) << 8;
    }

    // ---- staging addressing (global_load_lds, 16B/lane, LDS linear dest) ----
    // instr covers 16 rows x 64B; lane L -> row base+ (L>>2), chunk L&3.
    // Swizzle: LDS[r][c] = global[r][c ^ ((r>>1)&3)]; with r = 32w+16i+(L>>2)
    // the row term collapses: source chunk = (L&3) ^ ((L>>3)&3).
    const int srow = lane >> 2;
    const int csw  = ((lane & 3) ^ ((lane >> 3) & 3)) * 8;   // bf16 elems
    const unsigned short* Ag0 = A + (size_t)(bm + w * 32 + srow) * K + csw;
    const unsigned short* Ag1 = Ag0 + (size_t)16 * K;
    const unsigned short* Bg0 = B + (size_t)(bn + w * 32 + srow) * K + csw;
    const unsigned short* Bg1 = Bg0 + (size_t)16 * K;
    const int wA = w * 1024;          // wave's 32-row slab (elems)

    // ---- fragment read addressing (ds_read_b128) ----------------------------
    // lane = fm + 16q reads row fm, k-chunk q; swizzled chunk = q ^ ((fm>>1)&3)
    // -> per 8 rows all eight 16B bank-groups covered (2-way residual = free).
    const int fm   = lane & 15;
    const int q    = lane >> 4;
    const int rch  = (q ^ ((fm >> 1) & 3)) * 8;
    const int aoff = (wr * 128 + fm) * 32 + rch;
    const int boff = (wc * 64 + fm) * 32 + rch;

    floatx4 acc[8][4];
#pragma unroll
    for (int i = 0; i < 8; i++)
#pragma unroll
        for (int j = 0; j < 4; j++)
            acc[i][j] = (floatx4){0.f, 0.f, 0.f, 0.f};

    const int NT = K >> 5;            // 64 K-tiles (requires NT >= 3)

#define STAGE(t, b)                                                      \
    {                                                                    \
        const size_t k0 = (size_t)(t) << 5;                              \
        async_copy16(Ag0 + k0, &lA[(b)][wA]);                            \
        async_copy16(Ag1 + k0, &lA[(b)][wA + 512]);                      \
        async_copy16(Bg0 + k0, &lB[(b)][wA]);                            \
        async_copy16(Bg1 + k0, &lB[(b)][wA + 512]);                      \
    }

#define COMPUTE(b)                                                       \
    {                                                                    \
        bf16x8 af[8], bfv[4];                                            \
        _Pragma("unroll")                                                \
        for (int i = 0; i < 8; i++)                                      \
            af[i] = *(const bf16x8*)&lA[(b)][aoff + i * 512];            \
        _Pragma("unroll")                                                \
        for (int j = 0; j < 4; j++)                                      \
            bfv[j] = *(const bf16x8*)&lB[(b)][boff + j * 512];           \
        __builtin_amdgcn_s_setprio(1);                                   \
        _Pragma("unroll")                                                \
        for (int i = 0; i < 8; i++)                                      \
            _Pragma("unroll")                                            \
            for (int j = 0; j < 4; j++)                                  \
                acc[i][j] = __builtin_amdgcn_mfma_f32_16x16x32_bf16(     \
                    af[i], bfv[j], acc[i][j], 0, 0, 0);                  \
        __builtin_amdgcn_s_setprio(0);                                   \
    }

    // prologue: 3 tiles in flight
    STAGE(0, 0);
    STAGE(1, 1);
    STAGE(2, 2);

    for (int t = 0; t < NT - 2; ++t) {
        // tile t's 4 loads are the oldest; allow tiles t+1,t+2 (8) in flight.
        asm volatile("s_waitcnt vmcnt(8)" ::: "memory");
        __builtin_amdgcn_s_barrier();
        asm volatile("" ::: "memory");
        if (t + 3 < NT) STAGE(t + 3, (t + 3) & 3);
        COMPUTE(t & 3);
    }
    {   // t = NT-2: only tile NT-1 (4 loads) may remain in flight
        asm volatile("s_waitcnt vmcnt(4)" ::: "memory");
        __builtin_amdgcn_s_barrier();
        asm volatile("" ::: "memory");
        COMPUTE((NT - 2) & 3);
    }
    {   // t = NT-1: drain
        asm volatile("s_waitcnt vmcnt(0)" ::: "memory");
        __builtin_amdgcn_s_barrier();
        asm volatile("" ::: "memory");
        COMPUTE((NT - 1) & 3);
    }

#undef STAGE
#undef COMPUTE

    // epilogue: C/D layout col=lane&15, row=(lane>>4)*4+reg (m89-verified)
    const int cn  = lane & 15;
    const int cm4 = (lane >> 4) * 4;
#pragma unroll
    for (int j = 0; j < 4; j++) {
        const int col = bn + wc * 64 + j * 16 + cn;
        const float bv = bias[col];
#pragma unroll
        for (int i = 0; i < 8; i++) {
            const size_t rbase = (size_t)(bm + wr * 128 + i * 16 + cm4) * N + col;
#pragma unroll
            for (int r = 0; r < 4; r++)
                C[rbase + (size_t)r * N] = acc[i][j][r] + bv;
        }
    }
}

extern "C" void kernel_launch(void* const* d_in, const int* in_sizes, int n_in,
                              void* d_out, int out_size, void* d_ws, size_t ws_size,
                              hipStream_t stream) {
    const float* x    = (const float*)d_in[0];   // [S,B,H] fp32
    const float* w    = (const float*)d_in[1];   // [O,H]  fp32
    const float* bias = (const float*)d_in[2];   // [O]    fp32
    float* out = (float*)d_out;

    const int O = in_sizes[2];
    const int H = in_sizes[1] / O;
    const long M = (long)in_sizes[0] / H;        // S*B = 16384

    unsigned short* xb = (unsigned short*)d_ws;            // [M*H] bf16
    unsigned short* wb = xb + (size_t)M * H;               // [O*H] bf16

    const long n8 = (long)M * H / 8;
    cvt_bf16_x8<<<dim3((n8 + 255) / 256), dim3(256), 0, stream>>>(
        (const float4*)x, (uint4*)xb, n8);

    const int ng = O * H / 4;
    sparsify_w<<<dim3((ng + 255) / 256), dim3(256), 0, stream>>>(
        (const float4*)w, (unsigned long long*)wb, ng);

    const int nblocks = (int)((M / 256) * ((long)O / 256));   // 512, 1D grid
    gemm_bt_bf16_256<<<dim3(nblocks), dim3(512), 0, stream>>>(xb, wb, bias, out,
                                                              (int)M, O, H);
}

// Round 2
// 381.334 us; speedup vs baseline: 1.0656x; 1.0656x over previous
//
#include <hip/hip_runtime.h>
#include <stdint.h>

// ---------------------------------------------------------------------------
// RowParallelLinearSparse: out[M,N] = x[M,K] · (W ⊙ nm_mask(W))[N,K]^T + bias
// M=16384 (S*B), N=O=2048, K=H=2048.  bf16 MFMA.
//
// GEMM: 256x256 tile, BK=32, 8 waves (2Mx4N), ring-4 LDS buffers (128 KiB),
// counted s_waitcnt vmcnt(8), 2-PHASE per K-tile interleave (m201-style:
// {ds_reads ∥ stage-issue → barrier → lgkmcnt(0) → 16-MFMA cluster →
// barrier}), setprio(1) around each MFMA cluster, XOR-swizzled LDS
// (conflict-free, verified R1: SQ_LDS_BANK_CONFLICT=0), XCD-ownership
// N-column mapping (N/256 == 8 == #XCDs -> B slice L2-resident per XCD).
//
// Ring race-freedom (unchanged from R1, verified): STAGE(t+3)->buf[(t+3)&3]
// = buf[(t-1)&3] issues after tile t's first barrier; all waves' ds_reads of
// buf[(t-1)&3] are register-complete before that barrier (lgkmcnt before
// MFMA use); async LDS writes cannot land before issue. ds_reads of tile t
// are gated by {vmcnt(8) -> barrier} rendezvous at end of tile t-1.
// ---------------------------------------------------------------------------

typedef short  bf16x8  __attribute__((ext_vector_type(8)));
typedef float  floatx4 __attribute__((ext_vector_type(4)));

#define AS1 __attribute__((address_space(1)))
#define AS3 __attribute__((address_space(3)))

__device__ __forceinline__ void async_copy16(const void* g, void* l) {
    __builtin_amdgcn_global_load_lds((const AS1 unsigned int*)g,
                                     (AS3 unsigned int*)l, 16, 0, 0);
}

__device__ __forceinline__ unsigned short f2bf(float f) {
    union { float f; unsigned int u; } v;
    v.f = f;
    unsigned int r = (v.u + 0x7fffu + ((v.u >> 16) & 1u)) >> 16;  // RNE
    return (unsigned short)r;
}

// --- x: fp32 -> bf16. Contiguous-per-instruction lanes: wave handles 128
//     consecutive float4 (lane L: base+L and base+64+L), uint2 stores.
//     Grid-stride at 2048 blocks. ---------------------------------------------
__global__ void cvt_bf16_x8(const float4* __restrict__ in,
                            uint2* __restrict__ out, long n4) {
    const int lane = threadIdx.x & 63;
    const long wave   = ((long)blockIdx.x * blockDim.x + threadIdx.x) >> 6;
    const long nwaves = ((long)gridDim.x * blockDim.x) >> 6;
    for (long base = wave * 128; base < n4; base += nwaves * 128) {
        const long i0 = base + lane;
        const long i1 = base + 64 + lane;
        float4 f0 = in[i0];                    // lanes contiguous (16B/lane)
        float4 f1 = in[i1];
        uint2 o0, o1;
        o0.x = (unsigned)f2bf(f0.x) | ((unsigned)f2bf(f0.y) << 16);
        o0.y = (unsigned)f2bf(f0.z) | ((unsigned)f2bf(f0.w) << 16);
        o1.x = (unsigned)f2bf(f1.x) | ((unsigned)f2bf(f1.y) << 16);
        o1.y = (unsigned)f2bf(f1.z) | ((unsigned)f2bf(f1.w) << 16);
        out[i0] = o0;                          // lanes contiguous (8B/lane)
        out[i1] = o1;
    }
}

// --- W: 2:4 mask (zero 2 smallest |w| per group of 4, stable-argsort tie
//        order) -> bf16. One thread per group. -------------------------------
__global__ void sparsify_w(const float4* __restrict__ W,
                           unsigned long long* __restrict__ Wb, int ngroups) {
    int g = blockIdx.x * blockDim.x + threadIdx.x;
    if (g >= ngroups) return;
    float4 w4 = W[g];
    float v[4] = {w4.x, w4.y, w4.z, w4.w};
    float a[4] = {fabsf(w4.x), fabsf(w4.y), fabsf(w4.z), fabsf(w4.w)};
    unsigned long long packed = 0;
#pragma unroll
    for (int i = 0; i < 4; i++) {
        int rank = 0;
#pragma unroll
        for (int j = 0; j < 4; j++)
            rank += (a[j] < a[i]) || (a[j] == a[i] && j < i);
        unsigned short b = (rank >= 2) ? f2bf(v[i]) : (unsigned short)0;
        packed |= ((unsigned long long)b) << (16 * i);
    }
    Wb[g] = packed;
}

// --- bf16 B^T GEMM: 256x256 tile, BK=32, ring-4 + 2-phase interleave. -------
__global__ __launch_bounds__(512, 2) void gemm_bt_bf16_256(
    const unsigned short* __restrict__ A,   // [M,K] bf16
    const unsigned short* __restrict__ B,   // [N,K] bf16 (sparse W)
    const float* __restrict__ bias,         // [N]
    float* __restrict__ C,                  // [M,N] fp32
    int M, int N, int K) {
    __shared__ unsigned short lA[4][256 * 32];   // 64 KiB
    __shared__ unsigned short lB[4][256 * 32];   // 64 KiB

    const int tid  = threadIdx.x;
    const int w    = tid >> 6;       // wave 0..7
    const int lane = tid & 63;
    const int wr   = w >> 2;         // 0..1 : M-half of tile
    const int wc   = w & 3;          // 0..3 : N-quarter of tile

    // XCD-ownership mapping: 8 N-blocks == 8 XCDs (HW round-robins id&7).
    const int id  = blockIdx.x;
    const int nbx = N >> 8;
    int bm, bn;
    if (nbx == 8) {
        bn = (id & 7) << 8;
        bm = (id >> 3) << 8;
    } else {
        bn = (id % nbx) << 8;
        bm = (id / nbx) << 8;
    }

    // ---- staging addressing (global_load_lds, 16B/lane, LDS linear dest) ----
    // Swizzle: LDS[r][c] = global[r][c ^ ((r>>1)&3)]; with r = 32w+16i+(L>>2)
    // the row term collapses: source chunk = (L&3) ^ ((L>>3)&3).
    const int srow = lane >> 2;
    const int csw  = ((lane & 3) ^ ((lane >> 3) & 3)) * 8;   // bf16 elems
    const unsigned short* Ag0 = A + (size_t)(bm + w * 32 + srow) * K + csw;
    const unsigned short* Ag1 = Ag0 + (size_t)16 * K;
    const unsigned short* Bg0 = B + (size_t)(bn + w * 32 + srow) * K + csw;
    const unsigned short* Bg1 = Bg0 + (size_t)16 * K;
    const int wA = w * 1024;          // wave's 32-row slab (elems)

    // ---- fragment read addressing (ds_read_b128) ----------------------------
    // lane = fm + 16q reads row fm, k-chunk q; swizzled chunk = q ^ ((fm>>1)&3)
    const int fm   = lane & 15;
    const int q    = lane >> 4;
    const int rch  = (q ^ ((fm >> 1) & 3)) * 8;
    const int aoff = (wr * 128 + fm) * 32 + rch;
    const int boff = (wc * 64 + fm) * 32 + rch;

    floatx4 acc[8][4];
#pragma unroll
    for (int i = 0; i < 8; i++)
#pragma unroll
        for (int j = 0; j < 4; j++)
            acc[i][j] = (floatx4){0.f, 0.f, 0.f, 0.f};

    const int NT = K >> 5;            // 64 K-tiles (requires NT >= 4)

#define STAGE_A(t, b)                                                    \
    {                                                                    \
        const size_t k0 = (size_t)(t) << 5;                              \
        async_copy16(Ag0 + k0, &lA[(b)][wA]);                            \
        async_copy16(Ag1 + k0, &lA[(b)][wA + 512]);                      \
    }
#define STAGE_B(t, b)                                                    \
    {                                                                    \
        const size_t k0 = (size_t)(t) << 5;                              \
        async_copy16(Bg0 + k0, &lB[(b)][wA]);                            \
        async_copy16(Bg1 + k0, &lB[(b)][wA + 512]);                      \
    }
#define BAR()                                                            \
    {                                                                    \
        asm volatile("" ::: "memory");                                   \
        __builtin_amdgcn_s_barrier();                                    \
        asm volatile("" ::: "memory");                                   \
    }

    // prologue: 3 tiles in flight (issue order = tile order for vmcnt count)
    STAGE_A(0, 0); STAGE_B(0, 0);
    STAGE_A(1, 1); STAGE_B(1, 1);
    STAGE_A(2, 2); STAGE_B(2, 2);
    asm volatile("s_waitcnt vmcnt(8)" ::: "memory");  // tile 0 landed
    BAR();                                            // rendezvous for tile 0

    for (int t = 0; t < NT; ++t) {
        const int b  = t & 3;
        const int b3 = (t + 3) & 3;
        const bool do_stage = (t + 3) < NT;

        bf16x8 aF[8], bF[4];

        // ---- phase 0: A rows 0-3 + all B (8 reads) ∥ stage A(t+3) ----------
#pragma unroll
        for (int i = 0; i < 4; i++)
            aF[i] = *(const bf16x8*)&lA[b][aoff + i * 512];
#pragma unroll
        for (int j = 0; j < 4; j++)
            bF[j] = *(const bf16x8*)&lB[b][boff + j * 512];
        if (do_stage) STAGE_A(t + 3, b3);
        BAR();
        asm volatile("s_waitcnt lgkmcnt(0)" ::: "memory");
        __builtin_amdgcn_s_setprio(1);
#pragma unroll
        for (int i = 0; i < 4; i++)
#pragma unroll
            for (int j = 0; j < 4; j++)
                acc[i][j] = __builtin_amdgcn_mfma_f32_16x16x32_bf16(
                    aF[i], bF[j], acc[i][j], 0, 0, 0);
        __builtin_amdgcn_s_setprio(0);
        BAR();

        // ---- phase 1: A rows 4-7 (4 reads) ∥ stage B(t+3), vmcnt ------------
#pragma unroll
        for (int i = 0; i < 4; i++)
            aF[4 + i] = *(const bf16x8*)&lA[b][aoff + (4 + i) * 512];
        if (do_stage) STAGE_B(t + 3, b3);
        // rendezvous arithmetic: outstanding = t+1(4) + t+2(4) + t+3(4 if
        // staged); keep the two newest tiles in flight, complete tile t+1.
        if (t < NT - 3)       asm volatile("s_waitcnt vmcnt(8)" ::: "memory");
        else if (t == NT - 3) asm volatile("s_waitcnt vmcnt(4)" ::: "memory");
        else                  asm volatile("s_waitcnt vmcnt(0)" ::: "memory");
        BAR();
        asm volatile("s_waitcnt lgkmcnt(0)" ::: "memory");
        __builtin_amdgcn_s_setprio(1);
#pragma unroll
        for (int i = 0; i < 4; i++)
#pragma unroll
            for (int j = 0; j < 4; j++)
                acc[4 + i][j] = __builtin_amdgcn_mfma_f32_16x16x32_bf16(
                    aF[4 + i], bF[j], acc[4 + i][j], 0, 0, 0);
        __builtin_amdgcn_s_setprio(0);
        BAR();   // end barrier = rendezvous barrier for tile t+1's reads
    }

#undef STAGE_A
#undef STAGE_B
#undef BAR

    // epilogue: C/D layout col=lane&15, row=(lane>>4)*4+reg (m89-verified)
    const int cn  = lane & 15;
    const int cm4 = (lane >> 4) * 4;
#pragma unroll
    for (int j = 0; j < 4; j++) {
        const int col = bn + wc * 64 + j * 16 + cn;
        const float bv = bias[col];
#pragma unroll
        for (int i = 0; i < 8; i++) {
            const size_t rbase = (size_t)(bm + wr * 128 + i * 16 + cm4) * N + col;
#pragma unroll
            for (int r = 0; r < 4; r++)
                C[rbase + (size_t)r * N] = acc[i][j][r] + bv;
        }
    }
}

extern "C" void kernel_launch(void* const* d_in, const int* in_sizes, int n_in,
                              void* d_out, int out_size, void* d_ws, size_t ws_size,
                              hipStream_t stream) {
    const float* x    = (const float*)d_in[0];   // [S,B,H] fp32
    const float* w    = (const float*)d_in[1];   // [O,H]  fp32
    const float* bias = (const float*)d_in[2];   // [O]    fp32
    float* out = (float*)d_out;

    const int O = in_sizes[2];
    const int H = in_sizes[1] / O;
    const long M = (long)in_sizes[0] / H;        // S*B = 16384

    unsigned short* xb = (unsigned short*)d_ws;            // [M*H] bf16
    unsigned short* wb = xb + (size_t)M * H;               // [O*H] bf16

    const long n4 = (long)M * H / 4;
    cvt_bf16_x8<<<dim3(2048), dim3(256), 0, stream>>>(
        (const float4*)x, (uint2*)xb, n4);

    const int ng = O * H / 4;
    sparsify_w<<<dim3((ng + 255) / 256), dim3(256), 0, stream>>>(
        (const float4*)w, (unsigned long long*)wb, ng);

    const int nblocks = (int)((M / 256) * ((long)O / 256));   // 512, 1D grid
    gemm_bt_bf16_256<<<dim3(nblocks), dim3(512), 0, stream>>>(xb, wb, bias, out,
                                                              (int)M, O, H);
}